// Round 1
// baseline (680.049 us; speedup 1.0000x reference)
//
#include <hip/hip_runtime.h>

#define N_NODES 100000
#define N_EDGES 1600000
#define IN_F 128
#define H_F 64
#define C_F 16

// ---------------- GEMM1: H1 = X @ W1  (N x 128 @ 128 x 64) ----------------
// Thread = (node, out_feat). Wave of 64 lanes = one node's 64 output feats:
// X-row loads are wave-uniform (one broadcast fill), W1 in LDS (32 KB),
// lanes read w[k*64+f] stride-1 -> 2 lanes/bank (free per m136).
__global__ __launch_bounds__(256) void gemm1_kernel(
    const float* __restrict__ X, const float* __restrict__ W1,
    float* __restrict__ H1) {
  __shared__ float w[IN_F * H_F];
  for (int i = threadIdx.x; i < IN_F * H_F; i += 256) w[i] = W1[i];
  __syncthreads();
  int idx = blockIdx.x * 256 + threadIdx.x;
  if (idx >= N_NODES * H_F) return;
  int n = idx >> 6;
  int f = idx & 63;
  const float* xr = X + n * IN_F;
  float acc = 0.f;
#pragma unroll
  for (int k = 0; k < IN_F; ++k) acc += xr[k] * w[k * H_F + f];
  H1[idx] = acc;
}

// ---------------- init agg to broadcast bias ----------------
__global__ __launch_bounds__(256) void init_bias64_kernel(
    float* __restrict__ agg, const float* __restrict__ b) {
  int idx = blockIdx.x * 256 + threadIdx.x;
  if (idx < N_NODES * H_F) agg[idx] = b[idx & 63];
}

__global__ __launch_bounds__(256) void init_bias16_kernel(
    float* __restrict__ agg, const float* __restrict__ b) {
  int idx = blockIdx.x * 256 + threadIdx.x;
  if (idx < N_NODES * C_F) agg[idx] = b[idx & 15];
}

// ---------------- Scatter1: agg1 += w_e * H1[src]  (64 feats/edge) --------
// One wave per edge: lane = feat. Gather = 4 consecutive 64B lines of H1 row;
// atomic adds hit 4 consecutive lines of agg row. unsafeAtomicAdd -> HW
// global_atomic_add_f32 (device scope), not a CAS loop.
__global__ __launch_bounds__(256) void scatter1_kernel(
    const float* __restrict__ H1, const int* __restrict__ src,
    const int* __restrict__ dst, const float* __restrict__ ew,
    float* __restrict__ agg) {
  int t = blockIdx.x * 256 + threadIdx.x;
  int e = t >> 6;
  if (e >= N_EDGES) return;
  int f = t & 63;
  int s = src[e];
  int d = dst[e];
  float v = H1[s * H_F + f] * ew[e];
  unsafeAtomicAdd(&agg[d * H_F + f], v);
}

// ---------------- GEMM2: H2 = relu(agg1) @ W2  (N x 64 @ 64 x 16) ---------
// relu fused on read (agg1 was initialized with b1, so bias already applied).
__global__ __launch_bounds__(256) void gemm2_kernel(
    const float* __restrict__ agg1, const float* __restrict__ W2,
    float* __restrict__ H2) {
  __shared__ float w[H_F * C_F];
  for (int i = threadIdx.x; i < H_F * C_F; i += 256) w[i] = W2[i];
  __syncthreads();
  int idx = blockIdx.x * 256 + threadIdx.x;
  if (idx >= N_NODES * C_F) return;
  int n = idx >> 4;
  int f = idx & 15;
  const float* hr = agg1 + n * H_F;
  float acc = 0.f;
#pragma unroll
  for (int k = 0; k < H_F; ++k) {
    float h = hr[k];
    h = h > 0.f ? h : 0.f;
    acc += h * w[k * C_F + f];
  }
  H2[idx] = acc;
}

// ---------------- Scatter2: out += w_e * H2[src]  (16 feats/edge) ---------
__global__ __launch_bounds__(256) void scatter2_kernel(
    const float* __restrict__ H2, const int* __restrict__ src,
    const int* __restrict__ dst, const float* __restrict__ ew,
    float* __restrict__ out) {
  int t = blockIdx.x * 256 + threadIdx.x;
  int e = t >> 4;
  if (e >= N_EDGES) return;
  int f = t & 15;
  int s = src[e];
  int d = dst[e];
  float v = H2[s * C_F + f] * ew[e];
  unsafeAtomicAdd(&out[d * C_F + f], v);
}

extern "C" void kernel_launch(void* const* d_in, const int* in_sizes, int n_in,
                              void* d_out, int out_size, void* d_ws,
                              size_t ws_size, hipStream_t stream) {
  const float* X  = (const float*)d_in[0];
  const float* ew = (const float*)d_in[1];
  const float* W1 = (const float*)d_in[2];
  const float* b1 = (const float*)d_in[3];
  const float* W2 = (const float*)d_in[4];
  const float* b2 = (const float*)d_in[5];
  const int* src  = (const int*)d_in[6];
  const int* dst  = (const int*)d_in[7];
  float* out = (float*)d_out;

  // Workspace layout (51.2 MB total):
  //   [0, 25.6MB)      H1, later reused as H2 (H1 dead after scatter1)
  //   [25.6MB, 51.2MB) agg1
  float* H1   = (float*)d_ws;
  float* agg1 = H1 + (size_t)N_NODES * H_F;
  float* H2   = H1;  // reuse

  // Layer 1
  gemm1_kernel<<<(N_NODES * H_F + 255) / 256, 256, 0, stream>>>(X, W1, H1);
  init_bias64_kernel<<<(N_NODES * H_F + 255) / 256, 256, 0, stream>>>(agg1, b1);
  scatter1_kernel<<<(N_EDGES * 64 + 255) / 256, 256, 0, stream>>>(H1, src, dst,
                                                                  ew, agg1);
  // Layer 2 (relu fused into gemm2 read)
  gemm2_kernel<<<(N_NODES * C_F + 255) / 256, 256, 0, stream>>>(agg1, W2, H2);
  init_bias16_kernel<<<(N_NODES * C_F + 255) / 256, 256, 0, stream>>>(out, b2);
  scatter2_kernel<<<(N_EDGES * 16 + 255) / 256, 256, 0, stream>>>(H2, src, dst,
                                                                  ew, out);
}

// Round 2
// 559.769 us; speedup vs baseline: 1.2149x; 1.2149x over previous
//
#include <hip/hip_runtime.h>

#define N_NODES 100000
#define N_EDGES 1600000
#define IN_F 128
#define H_F 64
#define C_F 16

#define SCAN_NB 391  // ceil(100000/256)

// ---------------- GEMM1: H1 = X @ W1  (N x 128 @ 128 x 64) ----------------
__global__ __launch_bounds__(256) void gemm1_kernel(
    const float* __restrict__ X, const float* __restrict__ W1,
    float* __restrict__ H1) {
  __shared__ float w[IN_F * H_F];
  for (int i = threadIdx.x; i < IN_F * H_F; i += 256) w[i] = W1[i];
  __syncthreads();
  int idx = blockIdx.x * 256 + threadIdx.x;
  if (idx >= N_NODES * H_F) return;
  int n = idx >> 6;
  int f = idx & 63;
  const float* xr = X + n * IN_F;
  float acc = 0.f;
#pragma unroll
  for (int k = 0; k < IN_F; ++k) acc += xr[k] * w[k * H_F + f];
  H1[idx] = acc;
}

// ---------------- CSR build ----------------
__global__ __launch_bounds__(256) void zero_deg_kernel(int* __restrict__ deg) {
  int i = blockIdx.x * 256 + threadIdx.x;
  if (i < N_NODES) deg[i] = 0;
}

__global__ __launch_bounds__(256) void hist_kernel(
    const int* __restrict__ dst, int* __restrict__ deg) {
  int e = blockIdx.x * 256 + threadIdx.x;
  if (e < N_EDGES) atomicAdd(&deg[dst[e]], 1);
}

// block-level exclusive scan of deg -> offs, block totals -> blockSums
__global__ __launch_bounds__(256) void scan_a_kernel(
    const int* __restrict__ deg, int* __restrict__ offs,
    int* __restrict__ blockSums) {
  __shared__ int s[256];
  int i = blockIdx.x * 256 + threadIdx.x;
  int v = (i < N_NODES) ? deg[i] : 0;
  s[threadIdx.x] = v;
  __syncthreads();
#pragma unroll
  for (int d = 1; d < 256; d <<= 1) {
    int t = (threadIdx.x >= d) ? s[threadIdx.x - d] : 0;
    __syncthreads();
    s[threadIdx.x] += t;
    __syncthreads();
  }
  if (i < N_NODES) offs[i] = s[threadIdx.x] - v;  // exclusive
  if (threadIdx.x == 255) blockSums[blockIdx.x] = s[255];
}

// single-block exclusive scan of SCAN_NB block sums
__global__ __launch_bounds__(512) void scan_b_kernel(
    const int* __restrict__ blockSums, int* __restrict__ blockOffs,
    int* __restrict__ offs) {
  __shared__ int s[512];
  int v = (threadIdx.x < SCAN_NB) ? blockSums[threadIdx.x] : 0;
  s[threadIdx.x] = v;
  __syncthreads();
#pragma unroll
  for (int d = 1; d < 512; d <<= 1) {
    int t = (threadIdx.x >= d) ? s[threadIdx.x - d] : 0;
    __syncthreads();
    s[threadIdx.x] += t;
    __syncthreads();
  }
  if (threadIdx.x < SCAN_NB) blockOffs[threadIdx.x] = s[threadIdx.x] - v;
  if (threadIdx.x == 0) offs[N_NODES] = N_EDGES;  // total is known
}

// add block offsets, init cursor
__global__ __launch_bounds__(256) void scan_c_kernel(
    int* __restrict__ offs, const int* __restrict__ blockOffs,
    int* __restrict__ cursor) {
  int i = blockIdx.x * 256 + threadIdx.x;
  if (i < N_NODES) {
    int o = offs[i] + blockOffs[blockIdx.x];
    offs[i] = o;
    cursor[i] = o;
  }
}

// bucket edges by dst: es[pos]=src, ews[pos]=w
__global__ __launch_bounds__(256) void fill_kernel(
    const int* __restrict__ src, const int* __restrict__ dst,
    const float* __restrict__ ew, int* __restrict__ cursor,
    int* __restrict__ es, float* __restrict__ ews) {
  int e = blockIdx.x * 256 + threadIdx.x;
  if (e >= N_EDGES) return;
  int d = dst[e];
  int pos = atomicAdd(&cursor[d], 1);
  es[pos] = src[e];
  ews[pos] = ew[e];
}

// ---------------- Gather1: agg[n,f] = b1[f] + sum_in w_e * H1[src,f] ------
// One wave per node (64 lanes = 64 feats). No atomics. Unroll x2 for ILP.
__global__ __launch_bounds__(256) void gather1_kernel(
    const float* __restrict__ H1, const int* __restrict__ offs,
    const int* __restrict__ es, const float* __restrict__ ews,
    const float* __restrict__ b1, float* __restrict__ agg) {
  int t = blockIdx.x * 256 + threadIdx.x;
  int n = t >> 6;
  if (n >= N_NODES) return;
  int f = t & 63;
  int beg = offs[n];
  int end = offs[n + 1];
  float acc0 = b1[f];
  float acc1 = 0.f;
  int i = beg;
  for (; i + 1 < end; i += 2) {
    int s0 = es[i], s1 = es[i + 1];
    float w0 = ews[i], w1 = ews[i + 1];
    acc0 += H1[s0 * H_F + f] * w0;
    acc1 += H1[s1 * H_F + f] * w1;
  }
  if (i < end) acc0 += H1[es[i] * H_F + f] * ews[i];
  agg[n * H_F + f] = acc0 + acc1;
}

// ---------------- GEMM2: H2 = relu(agg1) @ W2  (N x 64 @ 64 x 16) ---------
__global__ __launch_bounds__(256) void gemm2_kernel(
    const float* __restrict__ agg1, const float* __restrict__ W2,
    float* __restrict__ H2) {
  __shared__ float w[H_F * C_F];
  for (int i = threadIdx.x; i < H_F * C_F; i += 256) w[i] = W2[i];
  __syncthreads();
  int idx = blockIdx.x * 256 + threadIdx.x;
  if (idx >= N_NODES * C_F) return;
  int n = idx >> 4;
  int f = idx & 15;
  const float* hr = agg1 + n * H_F;
  float acc = 0.f;
#pragma unroll
  for (int k = 0; k < H_F; ++k) {
    float h = hr[k];
    h = h > 0.f ? h : 0.f;
    acc += h * w[k * C_F + f];
  }
  H2[idx] = acc;
}

// ---------------- Gather2: out[n,f] = b2[f] + sum_in w_e * H2[src,f] ------
// 16 lanes per node (4 nodes per wave).
__global__ __launch_bounds__(256) void gather2_kernel(
    const float* __restrict__ H2, const int* __restrict__ offs,
    const int* __restrict__ es, const float* __restrict__ ews,
    const float* __restrict__ b2, float* __restrict__ out) {
  int t = blockIdx.x * 256 + threadIdx.x;
  int n = t >> 4;
  if (n >= N_NODES) return;
  int f = t & 15;
  int beg = offs[n];
  int end = offs[n + 1];
  float acc0 = b2[f];
  float acc1 = 0.f;
  int i = beg;
  for (; i + 1 < end; i += 2) {
    int s0 = es[i], s1 = es[i + 1];
    float w0 = ews[i], w1 = ews[i + 1];
    acc0 += H2[s0 * C_F + f] * w0;
    acc1 += H2[s1 * C_F + f] * w1;
  }
  if (i < end) acc0 += H2[es[i] * C_F + f] * ews[i];
  out[n * C_F + f] = acc0 + acc1;
}

extern "C" void kernel_launch(void* const* d_in, const int* in_sizes, int n_in,
                              void* d_out, int out_size, void* d_ws,
                              size_t ws_size, hipStream_t stream) {
  const float* X  = (const float*)d_in[0];
  const float* ew = (const float*)d_in[1];
  const float* W1 = (const float*)d_in[2];
  const float* b1 = (const float*)d_in[3];
  const float* W2 = (const float*)d_in[4];
  const float* b2 = (const float*)d_in[5];
  const int* src  = (const int*)d_in[6];
  const int* dst  = (const int*)d_in[7];
  float* out = (float*)d_out;

  // Workspace layout (~62 MiB total):
  float* H1   = (float*)d_ws;                         // 6.4M f  (25.6 MB), reused as H2
  float* agg1 = H1 + (size_t)N_NODES * H_F;           // 6.4M f  (25.6 MB)
  int* es     = (int*)(agg1 + (size_t)N_NODES * H_F); // 1.6M i  (6.4 MB)
  float* ews  = (float*)(es + N_EDGES);               // 1.6M f  (6.4 MB)
  int* offs   = (int*)(ews + N_EDGES);                // 100001 i
  int* deg    = offs + (N_NODES + 32);                // 100K i, reused as cursor
  int* cursor = deg;
  int* blockSums = deg + N_NODES;                     // 391 i
  int* blockOffs = blockSums + 512;                   // 391 i
  float* H2 = H1;

  const int nbN  = (N_NODES + 255) / 256;   // 391
  const int nbE  = (N_EDGES + 255) / 256;   // 6250

  // CSR build (dst-keyed; shared by both layers)
  zero_deg_kernel<<<nbN, 256, 0, stream>>>(deg);
  hist_kernel<<<nbE, 256, 0, stream>>>(dst, deg);
  scan_a_kernel<<<SCAN_NB, 256, 0, stream>>>(deg, offs, blockSums);
  scan_b_kernel<<<1, 512, 0, stream>>>(blockSums, blockOffs, offs);
  scan_c_kernel<<<SCAN_NB, 256, 0, stream>>>(offs, blockOffs, cursor);
  fill_kernel<<<nbE, 256, 0, stream>>>(src, dst, ew, cursor, es, ews);

  // Layer 1
  gemm1_kernel<<<(N_NODES * H_F + 255) / 256, 256, 0, stream>>>(X, W1, H1);
  gather1_kernel<<<(N_NODES * 64 + 255) / 256, 256, 0, stream>>>(
      H1, offs, es, ews, b1, agg1);
  // Layer 2
  gemm2_kernel<<<(N_NODES * C_F + 255) / 256, 256, 0, stream>>>(agg1, W2, H2);
  gather2_kernel<<<(N_NODES * C_F + 255) / 256, 256, 0, stream>>>(
      H2, offs, es, ews, b2, out);
}

// Round 3
// 447.466 us; speedup vs baseline: 1.5198x; 1.2510x over previous
//
#include <hip/hip_runtime.h>

#define N_NODES 100000
#define N_EDGES 1600000
#define IN_F 128
#define H_F 64
#define C_F 16

#define SCAN_NB 391  // ceil(100000/256)

typedef __attribute__((ext_vector_type(8))) short bf16x8;  // 8 bf16 (4 VGPRs)
typedef __attribute__((ext_vector_type(4))) float f32x4;   // MFMA C/D

// fp32 -> bf16 round-to-nearest-even (inputs are finite; no NaN handling)
__device__ inline short f2bf(float f) {
  unsigned u = __float_as_uint(f);
  unsigned r = (u + 0x7fff + ((u >> 16) & 1)) >> 16;
  return (short)r;
}

// ---------------- GEMM1 (MFMA): H1 = X @ W1  (100000 x 128 @ 128 x 64) ----
// One wave computes a 16(node) x 64(feat) tile: 4 col-tiles x 4 k-steps of
// mfma_f32_16x16x32_bf16. B (=W1) fragments are pre-swizzled into LDS in
// exact per-lane order so each B load is a single dense ds_read_b128.
// A layout [m=lane&15][k=quad*8+j] -> lane reads 32B of its X row, coalesced.
__global__ __launch_bounds__(256) void gemm1_mfma_kernel(
    const float* __restrict__ X, const float* __restrict__ W1,
    float* __restrict__ H1) {
  __shared__ short ldsB[16 * 512];  // 16 frags x (64 lanes x 8 bf16) = 16 KB
  for (int idx = threadIdx.x; idx < 16 * 512; idx += 256) {
    int frag = idx >> 9;    // c*4 + s
    int entry = idx & 511;  // lane*8 + j
    int lane = entry >> 3, j = entry & 7;
    int c = frag >> 2, s = frag & 3;
    int k = s * 32 + (lane >> 4) * 8 + j;
    int n = c * 16 + (lane & 15);
    ldsB[idx] = f2bf(W1[k * H_F + n]);
  }
  __syncthreads();

  int wave = threadIdx.x >> 6;
  int lane = threadIdx.x & 63;
  int rt = blockIdx.x * 4 + wave;  // row (node) tile, 16 nodes each
  if (rt >= N_NODES / 16) return;  // 6250 tiles exactly
  int node0 = rt * 16;
  int l = lane & 15, q = lane >> 4;

  const float* xp = X + (size_t)(node0 + l) * IN_F + q * 8;
  f32x4 acc[4] = {f32x4{0.f, 0.f, 0.f, 0.f}, f32x4{0.f, 0.f, 0.f, 0.f},
                  f32x4{0.f, 0.f, 0.f, 0.f}, f32x4{0.f, 0.f, 0.f, 0.f}};
#pragma unroll
  for (int s = 0; s < 4; ++s) {
    float4 x0 = *(const float4*)(xp + s * 32);
    float4 x1 = *(const float4*)(xp + s * 32 + 4);
    bf16x8 a;
    a[0] = f2bf(x0.x); a[1] = f2bf(x0.y); a[2] = f2bf(x0.z); a[3] = f2bf(x0.w);
    a[4] = f2bf(x1.x); a[5] = f2bf(x1.y); a[6] = f2bf(x1.z); a[7] = f2bf(x1.w);
#pragma unroll
    for (int c = 0; c < 4; ++c) {
      bf16x8 b = *(const bf16x8*)&ldsB[(c * 4 + s) * 512 + lane * 8];
      acc[c] = __builtin_amdgcn_mfma_f32_16x16x32_bf16(a, b, acc[c], 0, 0, 0);
    }
  }
  // C/D: col = lane&15 (feat offset), row = q*4 + reg (node offset)
#pragma unroll
  for (int c = 0; c < 4; ++c)
#pragma unroll
    for (int r = 0; r < 4; ++r)
      H1[(size_t)(node0 + q * 4 + r) * H_F + c * 16 + l] = acc[c][r];
}

// ---------------- CSR build ----------------
__global__ __launch_bounds__(256) void zero_deg_kernel(int* __restrict__ deg) {
  int i = blockIdx.x * 256 + threadIdx.x;
  if (i < N_NODES) deg[i] = 0;
}

__global__ __launch_bounds__(256) void hist_kernel(
    const int* __restrict__ dst, int* __restrict__ deg) {
  int e = blockIdx.x * 256 + threadIdx.x;
  if (e < N_EDGES) atomicAdd(&deg[dst[e]], 1);
}

__global__ __launch_bounds__(256) void scan_a_kernel(
    const int* __restrict__ deg, int* __restrict__ offs,
    int* __restrict__ blockSums) {
  __shared__ int s[256];
  int i = blockIdx.x * 256 + threadIdx.x;
  int v = (i < N_NODES) ? deg[i] : 0;
  s[threadIdx.x] = v;
  __syncthreads();
#pragma unroll
  for (int d = 1; d < 256; d <<= 1) {
    int t = (threadIdx.x >= d) ? s[threadIdx.x - d] : 0;
    __syncthreads();
    s[threadIdx.x] += t;
    __syncthreads();
  }
  if (i < N_NODES) offs[i] = s[threadIdx.x] - v;  // exclusive
  if (threadIdx.x == 255) blockSums[blockIdx.x] = s[255];
}

__global__ __launch_bounds__(512) void scan_b_kernel(
    const int* __restrict__ blockSums, int* __restrict__ blockOffs,
    int* __restrict__ offs) {
  __shared__ int s[512];
  int v = (threadIdx.x < SCAN_NB) ? blockSums[threadIdx.x] : 0;
  s[threadIdx.x] = v;
  __syncthreads();
#pragma unroll
  for (int d = 1; d < 512; d <<= 1) {
    int t = (threadIdx.x >= d) ? s[threadIdx.x - d] : 0;
    __syncthreads();
    s[threadIdx.x] += t;
    __syncthreads();
  }
  if (threadIdx.x < SCAN_NB) blockOffs[threadIdx.x] = s[threadIdx.x] - v;
  if (threadIdx.x == 0) offs[N_NODES] = N_EDGES;
}

__global__ __launch_bounds__(256) void scan_c_kernel(
    int* __restrict__ offs, const int* __restrict__ blockOffs,
    int* __restrict__ cursor) {
  int i = blockIdx.x * 256 + threadIdx.x;
  if (i < N_NODES) {
    int o = offs[i] + blockOffs[blockIdx.x];
    offs[i] = o;
    cursor[i] = o;
  }
}

__global__ __launch_bounds__(256) void fill_kernel(
    const int* __restrict__ src, const int* __restrict__ dst,
    const float* __restrict__ ew, int* __restrict__ cursor,
    int* __restrict__ es, float* __restrict__ ews) {
  int e = blockIdx.x * 256 + threadIdx.x;
  if (e >= N_EDGES) return;
  int d = dst[e];
  int pos = atomicAdd(&cursor[d], 1);
  es[pos] = src[e];
  ews[pos] = ew[e];
}

// ---------------- Gather1: agg[n,f] = b1[f] + sum_in w_e * H1[src,f] ------
__global__ __launch_bounds__(256) void gather1_kernel(
    const float* __restrict__ H1, const int* __restrict__ offs,
    const int* __restrict__ es, const float* __restrict__ ews,
    const float* __restrict__ b1, float* __restrict__ agg) {
  int t = blockIdx.x * 256 + threadIdx.x;
  int n = t >> 6;
  if (n >= N_NODES) return;
  int f = t & 63;
  int beg = offs[n];
  int end = offs[n + 1];
  float acc0 = b1[f];
  float acc1 = 0.f;
  int i = beg;
  for (; i + 1 < end; i += 2) {
    int s0 = es[i], s1 = es[i + 1];
    float w0 = ews[i], w1 = ews[i + 1];
    acc0 += H1[s0 * H_F + f] * w0;
    acc1 += H1[s1 * H_F + f] * w1;
  }
  if (i < end) acc0 += H1[es[i] * H_F + f] * ews[i];
  agg[n * H_F + f] = acc0 + acc1;
}

// ---------------- GEMM2: H2 = relu(agg1) @ W2  (N x 64 @ 64 x 16) ---------
__global__ __launch_bounds__(256) void gemm2_kernel(
    const float* __restrict__ agg1, const float* __restrict__ W2,
    float* __restrict__ H2) {
  __shared__ float w[H_F * C_F];
  for (int i = threadIdx.x; i < H_F * C_F; i += 256) w[i] = W2[i];
  __syncthreads();
  int idx = blockIdx.x * 256 + threadIdx.x;
  if (idx >= N_NODES * C_F) return;
  int n = idx >> 4;
  int f = idx & 15;
  const float* hr = agg1 + n * H_F;
  float acc = 0.f;
#pragma unroll
  for (int k = 0; k < H_F; ++k) {
    float h = hr[k];
    h = h > 0.f ? h : 0.f;
    acc += h * w[k * C_F + f];
  }
  H2[idx] = acc;
}

// ---------------- Gather2: out[n,f] = b2[f] + sum_in w_e * H2[src,f] ------
__global__ __launch_bounds__(256) void gather2_kernel(
    const float* __restrict__ H2, const int* __restrict__ offs,
    const int* __restrict__ es, const float* __restrict__ ews,
    const float* __restrict__ b2, float* __restrict__ out) {
  int t = blockIdx.x * 256 + threadIdx.x;
  int n = t >> 4;
  if (n >= N_NODES) return;
  int f = t & 15;
  int beg = offs[n];
  int end = offs[n + 1];
  float acc0 = b2[f];
  float acc1 = 0.f;
  int i = beg;
  for (; i + 1 < end; i += 2) {
    int s0 = es[i], s1 = es[i + 1];
    float w0 = ews[i], w1 = ews[i + 1];
    acc0 += H2[s0 * C_F + f] * w0;
    acc1 += H2[s1 * C_F + f] * w1;
  }
  if (i < end) acc0 += H2[es[i] * C_F + f] * ews[i];
  out[n * C_F + f] = acc0 + acc1;
}

extern "C" void kernel_launch(void* const* d_in, const int* in_sizes, int n_in,
                              void* d_out, int out_size, void* d_ws,
                              size_t ws_size, hipStream_t stream) {
  const float* X  = (const float*)d_in[0];
  const float* ew = (const float*)d_in[1];
  const float* W1 = (const float*)d_in[2];
  const float* b1 = (const float*)d_in[3];
  const float* W2 = (const float*)d_in[4];
  const float* b2 = (const float*)d_in[5];
  const int* src  = (const int*)d_in[6];
  const int* dst  = (const int*)d_in[7];
  float* out = (float*)d_out;

  float* H1   = (float*)d_ws;                         // 25.6 MB, reused as H2
  float* agg1 = H1 + (size_t)N_NODES * H_F;           // 25.6 MB
  int* es     = (int*)(agg1 + (size_t)N_NODES * H_F); // 6.4 MB
  float* ews  = (float*)(es + N_EDGES);               // 6.4 MB
  int* offs   = (int*)(ews + N_EDGES);                // 100001 i
  int* deg    = offs + (N_NODES + 32);                // 100K i (reused cursor)
  int* cursor = deg;
  int* blockSums = deg + N_NODES;
  int* blockOffs = blockSums + 512;
  float* H2 = H1;

  const int nbN = (N_NODES + 255) / 256;  // 391
  const int nbE = (N_EDGES + 255) / 256;  // 6250

  // CSR build (dst-keyed; shared by both layers)
  zero_deg_kernel<<<nbN, 256, 0, stream>>>(deg);
  hist_kernel<<<nbE, 256, 0, stream>>>(dst, deg);
  scan_a_kernel<<<SCAN_NB, 256, 0, stream>>>(deg, offs, blockSums);
  scan_b_kernel<<<1, 512, 0, stream>>>(blockSums, blockOffs, offs);
  scan_c_kernel<<<SCAN_NB, 256, 0, stream>>>(offs, blockOffs, cursor);
  fill_kernel<<<nbE, 256, 0, stream>>>(src, dst, ew, cursor, es, ews);

  // Layer 1
  gemm1_mfma_kernel<<<(N_NODES / 16 + 3) / 4, 256, 0, stream>>>(X, W1, H1);
  gather1_kernel<<<(N_NODES * 64 + 255) / 256, 256, 0, stream>>>(
      H1, offs, es, ews, b1, agg1);
  // Layer 2
  gemm2_kernel<<<(N_NODES * C_F + 255) / 256, 256, 0, stream>>>(agg1, W2, H2);
  gather2_kernel<<<(N_NODES * C_F + 255) / 256, 256, 0, stream>>>(
      H2, offs, es, ews, b2, out);
}